// Round 4
// baseline (198.458 us; speedup 1.0000x reference)
//
#include <hip/hip_runtime.h>
#include <hip/hip_bf16.h>

// Problem constants (match reference)
#define RR 3
#define NN 8192
#define BB 4096
#define IN_DIM 256
#define HID 128
#define OUT 64
#define CAPD 128     // padded list capacity (unique nbr nodes ~ Binom(3224,0.01) ~ 32±5.7)
#define EPS 1e-5f
#define MWN (NN / 64)   // 128 mask words over node space

// ---- prep: multiplicity, membership bitmap, rank compaction, pos->slot ----
__global__ __launch_bounds__(1024) void prep_k(const int* __restrict__ bn,
                                               unsigned long long* __restrict__ memb,
                                               unsigned short* __restrict__ rankg,
                                               unsigned short* __restrict__ nodeof,
                                               float* __restrict__ multf,
                                               int* __restrict__ Ucnt,
                                               unsigned short* __restrict__ pos2slot) {
    __shared__ int smult[NN];                 // 32 KB
    __shared__ unsigned short srank[NN];      // 16 KB
    __shared__ unsigned long long smemb[MWN]; // 1 KB
    __shared__ int sbase[MWN + 1];
    int t = threadIdx.x;
    for (int u = t; u < NN; u += 1024) smult[u] = 0;
    __syncthreads();
    for (int i = t; i < BB; i += 1024) atomicAdd(&smult[bn[i]], 1);
    __syncthreads();
    if (t < MWN) {
        unsigned long long w = 0;
        for (int b = 0; b < 64; ++b) if (smult[t * 64 + b]) w |= (1ull << b);
        smemb[t] = w;
        memb[t] = w;
    }
    __syncthreads();
    if (t == 0) {
        int acc = 0;
        for (int m = 0; m < MWN; ++m) { sbase[m] = acc; acc += (int)__popcll(smemb[m]); }
        sbase[MWN] = acc;
        *Ucnt = acc;
    }
    __syncthreads();
    if (t < MWN) {
        unsigned long long w = smemb[t];
        int p = sbase[t];
        while (w) {
            int b = __builtin_ctzll(w); w &= w - 1;
            int u = t * 64 + b;
            srank[u] = (unsigned short)p;
            rankg[u] = (unsigned short)p;
            nodeof[p] = (unsigned short)u;
            multf[p]  = (float)smult[u];
            ++p;
        }
    }
    __syncthreads();
    for (int i = t; i < BB; i += 1024) pos2slot[i] = srank[bn[i]];
}

// ---- BN1 partial stats: slot-major coalesced, multiplicity-weighted ----
__global__ __launch_bounds__(256) void bn1_partial_k(const float* __restrict__ feat,
                                                     const unsigned short* __restrict__ nodeof,
                                                     const float* __restrict__ multf,
                                                     const int* __restrict__ Ucnt,
                                                     float* __restrict__ partial) {
    int b = blockIdx.x;   // 64 blocks x 64 slots
    int c = threadIdx.x;
    int U = *Ucnt;
    float s = 0.f, q = 0.f;
    for (int t = 0; t < 64; ++t) {
        int sl = b * 64 + t;
        if (sl >= U) break;
        float m = multf[sl];
        float v = feat[(size_t)nodeof[sl] * IN_DIM + c];
        s += m * v; q += m * v * v;
    }
    partial[(size_t)(2 * b) * IN_DIM + c]     = s;
    partial[(size_t)(2 * b + 1) * IN_DIM + c] = q;
}

__global__ __launch_bounds__(256) void bn1_final_k(const float* __restrict__ partial,
                                                   float* __restrict__ m1,
                                                   float* __restrict__ rs1) {
    int c = threadIdx.x;
    float S = 0.f, Q = 0.f;
    for (int b = 0; b < 64; ++b) {
        S += partial[(size_t)(2 * b) * IN_DIM + c];
        Q += partial[(size_t)(2 * b + 1) * IN_DIM + c];
    }
    float m = S / BB;                       // sum of multiplicities == BB
    m1[c] = m;
    rs1[c] = rsqrtf(Q / BB - m * m + EPS);  // biased variance
}

// ---- xn per unique node slot: xn_c[s] = BN1(feat[nodeof[s]]) ----
__global__ __launch_bounds__(256) void xn_c_k(const float* __restrict__ feat,
                                              const unsigned short* __restrict__ nodeof,
                                              const int* __restrict__ Ucnt,
                                              const float* __restrict__ m1,
                                              const float* __restrict__ rs1,
                                              const float* __restrict__ g1,
                                              const float* __restrict__ b1,
                                              float* __restrict__ xn_c) {
    int s = blockIdx.x;
    if (s >= *Ucnt) return;
    int u = nodeof[s];
    int c = threadIdx.x;
    float v = feat[(size_t)u * IN_DIM + c];
    xn_c[(size_t)s * IN_DIM + c] = (v - m1[c]) * rs1[c] * g1[c] + b1[c];
}

// ---- build per (r, slot): coalesced row read -> bits -> AND membership -> list ----
__global__ __launch_bounds__(256) void build_k(const float* __restrict__ adj,
                                               const unsigned short* __restrict__ nodeof,
                                               const int* __restrict__ Ucnt,
                                               const unsigned long long* __restrict__ memb,
                                               const unsigned short* __restrict__ rankg,
                                               const float* __restrict__ multf,
                                               unsigned short* __restrict__ cols,
                                               int* __restrict__ cnt,
                                               float* __restrict__ dinv) {
    int blk = blockIdx.x;                   // r*4096 + s
    int r = blk >> 12, s = blk & (BB - 1);
    if (s >= *Ucnt) return;
    int u = nodeof[s];
    __shared__ unsigned char nib[2048];
    __shared__ unsigned int rawb[256];
    __shared__ unsigned long long sel[MWN];
    __shared__ int sbase[MWN + 1];
    __shared__ float pdeg[4];
    int t = threadIdx.x;
    // phase A: coalesced read of the 8192-float adjacency row; compress to bits
    const float4* ar4 = (const float4*)(adj + ((size_t)r * NN + u) * NN);
    #pragma unroll
    for (int ch = 0; ch < 8; ++ch) {
        float4 v = ar4[ch * 256 + t];
        nib[ch * 256 + t] = (unsigned char)((v.x != 0.f) | ((v.y != 0.f) << 1) |
                                            ((v.z != 0.f) << 2) | ((v.w != 0.f) << 3));
    }
    __syncthreads();
    {   // assemble u32 word t: cols [32t, 32t+32)
        unsigned long long x = *(const unsigned long long*)&nib[t * 8];
        x = (x | (x >> 4))  & 0x00FF00FF00FF00FFull;
        x = (x | (x >> 8))  & 0x0000FFFF0000FFFFull;
        x = (x | (x >> 16));
        rawb[t] = (unsigned int)x;
    }
    __syncthreads();
    // phase B: select member columns = raw & memb
    if (t < MWN) {
        unsigned long long w = ((unsigned long long)rawb[2 * t + 1] << 32) | rawb[2 * t];
        sel[t] = w & memb[t];
    }
    __syncthreads();
    // phase C: exclusive scan of word popcounts (wave 0, 2 words/lane)
    if (t < 64) {
        int p0 = (int)__popcll(sel[2 * t]);
        int p1 = (int)__popcll(sel[2 * t + 1]);
        int x = p0 + p1, xs = x;
        for (int o = 1; o < 64; o <<= 1) { int y = __shfl_up(xs, o); if (t >= o) xs += y; }
        sbase[2 * t]     = xs - x;
        sbase[2 * t + 1] = xs - p1;
        if (t == 63) sbase[MWN] = xs;
    }
    __syncthreads();
    // phase D: emit slot list + multiplicity-weighted degree
    float wdeg = 0.f;
    if (t < MWN) {
        unsigned long long w = sel[t];
        int p = sbase[t];
        unsigned short* cb = cols + (size_t)blk * CAPD;
        while (w) {
            int b = __builtin_ctzll(w); w &= w - 1;
            int v = t * 64 + b;
            int rv = rankg[v];
            if (p < CAPD) cb[p] = (unsigned short)rv;
            wdeg += multf[rv];
            ++p;
        }
    }
    int lane = t & 63, wv = t >> 6;
    for (int o = 32; o; o >>= 1) wdeg += __shfl_down(wdeg, o);
    if (lane == 0) pdeg[wv] = wdeg;
    __syncthreads();
    if (t == 0) {
        int tot = sbase[MWN];
        cnt[blk] = tot < CAPD ? tot : CAPD;
        dinv[blk] = rsqrtf(pdeg[0] + pdeg[1] + pdeg[2] + pdeg[3] + 1.0f);  // +1 from eye
    }
}

// ---- layer1: 4 slots/block; wave-per-slot float4 agg; shared-w1 GEMM ----
__global__ __launch_bounds__(256) void layer1_k(const float* __restrict__ xn_c,
                                                const unsigned short* __restrict__ cols,
                                                const int* __restrict__ cnt,
                                                const float* __restrict__ dinv,
                                                const float* __restrict__ multf,
                                                const int* __restrict__ Ucnt,
                                                const float* __restrict__ w1,
                                                float* __restrict__ h1) {
    int blk = blockIdx.x;                // r*1024 + q
    int r = blk >> 10, base = (blk & 1023) << 2;
    int U = *Ucnt;
    int tid = threadIdx.x, lane = tid & 63, wv = tid >> 6;
    __shared__ unsigned short scl[4][CAPD];
    __shared__ float swl[4][CAPD];
    __shared__ float ys[4][IN_DIM];
    __shared__ float sdi[4];
    int slot = base + wv;
    int n = (slot < U) ? cnt[(r << 12) + slot] : 0;
    if (lane == 0) sdi[wv] = (slot < U) ? dinv[(r << 12) + slot] : 0.f;
    size_t cb = ((size_t)(r << 12) + slot) * CAPD;
    for (int idx = lane; idx < n; idx += 64) {
        int sl = cols[cb + idx];
        scl[wv][idx] = (unsigned short)sl;
        swl[wv][idx] = multf[sl] * dinv[(r << 12) + sl];
    }
    __syncthreads();
    {   // aggregation: wave wv owns slot (base+wv); float4 across 256 cols
        float di = sdi[wv];
        float4 acc = make_float4(0.f, 0.f, 0.f, 0.f);
        if (slot < U) {
            float4 xv = ((const float4*)(xn_c + (size_t)slot * IN_DIM))[lane];
            acc.x = di * xv.x; acc.y = di * xv.y; acc.z = di * xv.z; acc.w = di * xv.w;
        }
        #pragma unroll 4
        for (int k = 0; k < n; ++k) {
            float4 xv = ((const float4*)(xn_c + (size_t)scl[wv][k] * IN_DIM))[lane];
            float wk = swl[wv][k];
            acc.x += wk * xv.x; acc.y += wk * xv.y; acc.z += wk * xv.z; acc.w += wk * xv.w;
        }
        acc.x *= di; acc.y *= di; acc.z *= di; acc.w *= di;
        *(float4*)&ys[wv][lane * 4] = acc;
    }
    __syncthreads();
    // GEMM: thread t -> col c = t&127, pair h = t>>7 covers slots h and h+2
    int c = tid & 127, h = tid >> 7;
    float z0 = 0.f, z1 = 0.f;
    #pragma unroll 8
    for (int k = 0; k < IN_DIM; ++k) {
        float wvl = w1[k * HID + c];
        z0 += ys[h][k] * wvl;
        z1 += ys[h + 2][k] * wvl;
    }
    float e0 = z0 > 0.f ? z0 : expm1f(z0);
    h1[((size_t)(r << 12) + base + h) * HID + c] = 1.f / (1.f + expf(-e0));
    float e1 = z1 > 0.f ? z1 : expm1f(z1);
    h1[((size_t)(r << 12) + base + h + 2) * HID + c] = 1.f / (1.f + expf(-e1));
}

// ---- layer2: 4 slots/block; wave-per-slot float2 agg; shared-w2 GEMM ----
__global__ __launch_bounds__(256) void layer2_k(const float* __restrict__ h1,
                                                const unsigned short* __restrict__ cols,
                                                const int* __restrict__ cnt,
                                                const float* __restrict__ dinv,
                                                const float* __restrict__ multf,
                                                const int* __restrict__ Ucnt,
                                                const float* __restrict__ w2,
                                                float* __restrict__ h2) {
    int blk = blockIdx.x;
    int r = blk >> 10, base = (blk & 1023) << 2;
    int U = *Ucnt;
    int tid = threadIdx.x, lane = tid & 63, wv = tid >> 6;
    __shared__ unsigned short scl[4][CAPD];
    __shared__ float swl[4][CAPD];
    __shared__ float ys[4][HID];
    __shared__ float sdi[4];
    int slot = base + wv;
    int n = (slot < U) ? cnt[(r << 12) + slot] : 0;
    if (lane == 0) sdi[wv] = (slot < U) ? dinv[(r << 12) + slot] : 0.f;
    size_t cb = ((size_t)(r << 12) + slot) * CAPD;
    for (int idx = lane; idx < n; idx += 64) {
        int sl = cols[cb + idx];
        scl[wv][idx] = (unsigned short)sl;
        swl[wv][idx] = multf[sl] * dinv[(r << 12) + sl];
    }
    __syncthreads();
    const float* h1r = h1 + ((size_t)(r << 12)) * HID;
    {
        float di = sdi[wv];
        float2 acc = make_float2(0.f, 0.f);
        if (slot < U) {
            float2 xv = ((const float2*)(h1r + (size_t)slot * HID))[lane];
            acc.x = di * xv.x; acc.y = di * xv.y;
        }
        #pragma unroll 4
        for (int k = 0; k < n; ++k) {
            float2 xv = ((const float2*)(h1r + (size_t)scl[wv][k] * HID))[lane];
            float wk = swl[wv][k];
            acc.x += wk * xv.x; acc.y += wk * xv.y;
        }
        acc.x *= di; acc.y *= di;
        ys[wv][lane * 2] = acc.x; ys[wv][lane * 2 + 1] = acc.y;
    }
    __syncthreads();
    // GEMM: 256 threads -> (slot g = t>>6, col c = t&63)
    int c = tid & 63, g = tid >> 6;
    float z = 0.f;
    #pragma unroll 8
    for (int k = 0; k < HID; ++k) z += ys[g][k] * w2[k * OUT + c];
    float e = z > 0.f ? z : expm1f(z);
    h2[((size_t)(r << 12) + base + g) * OUT + c] = e;
}

// ---- BN2 stats per (relation, column): multiplicity-weighted over slots ----
__global__ __launch_bounds__(256) void bn2_stats_k(const float* __restrict__ h2,
                                                   const float* __restrict__ multf,
                                                   const int* __restrict__ Ucnt,
                                                   float* __restrict__ m2,
                                                   float* __restrict__ rs2) {
    int ro = blockIdx.x;             // r*OUT + o
    int r = ro >> 6, o = ro & (OUT - 1);
    int U = *Ucnt;
    float s = 0.f, q = 0.f;
    for (int sl = threadIdx.x; sl < U; sl += 256) {
        float m = multf[sl];
        float v = h2[(size_t)((r << 12) + sl) * OUT + o];
        s += m * v; q += m * v * v;
    }
    int lane = threadIdx.x & 63, wv = threadIdx.x >> 6;
    for (int off = 32; off; off >>= 1) { s += __shfl_down(s, off); q += __shfl_down(q, off); }
    __shared__ float ps[4], pq[4];
    if (lane == 0) { ps[wv] = s; pq[wv] = q; }
    __syncthreads();
    if (threadIdx.x == 0) {
        float S = ps[0] + ps[1] + ps[2] + ps[3];
        float Q = pq[0] + pq[1] + pq[2] + pq[3];
        float m = S / BB;                 // sum of mult == BB positions
        float v = Q / BB - m * m;
        m2[ro] = m;
        rs2[ro] = rsqrtf(v + EPS);
    }
}

// ---- finalize: out[i] = relu(mean_r BN2(h2[r, slot(i)])) ----
__global__ __launch_bounds__(256) void finalize_k(const float* __restrict__ h2,
                                                  const unsigned short* __restrict__ pos2slot,
                                                  const float* __restrict__ m2,
                                                  const float* __restrict__ rs2,
                                                  const float* __restrict__ g2,
                                                  const float* __restrict__ b2,
                                                  float* __restrict__ out) {
    int idx = blockIdx.x * 256 + threadIdx.x;  // i*OUT + o
    if (idx >= BB * OUT) return;
    int i = idx >> 6, o = idx & (OUT - 1);
    int sl = pos2slot[i];
    float s = 0.f;
    for (int r = 0; r < RR; ++r) {
        float v = h2[(size_t)((r << 12) + sl) * OUT + o];
        s += (v - m2[r * OUT + o]) * rs2[r * OUT + o] * g2[o] + b2[o];
    }
    s *= (1.0f / RR);
    out[idx] = s > 0.f ? s : 0.f;
}

extern "C" void kernel_launch(void* const* d_in, const int* in_sizes, int n_in,
                              void* d_out, int out_size, void* d_ws, size_t ws_size,
                              hipStream_t stream) {
    const float* feat = (const float*)d_in[0];
    const float* adj  = (const float*)d_in[1];
    const int*   bn   = (const int*)d_in[2];
    const float* w1   = (const float*)d_in[3];
    const float* w2   = (const float*)d_in[4];
    const float* g1   = (const float*)d_in[5];
    const float* b1   = (const float*)d_in[6];
    const float* g2   = (const float*)d_in[7];
    const float* b2   = (const float*)d_in[8];
    float* out = (float*)d_out;

    // workspace layout (256-aligned offsets)
    char* ws = (char*)d_ws;
    size_t off = 0;
    auto alloc = [&](size_t bytes) { size_t o = off; off += (bytes + 255) & ~(size_t)255; return o; };
    unsigned long long* memb = (unsigned long long*)(ws + alloc(MWN * 8));      // 1 KB
    unsigned short* rankg    = (unsigned short*)(ws + alloc(NN * 2));           // 16 KB
    unsigned short* nodeof   = (unsigned short*)(ws + alloc(BB * 2));           // 8 KB
    float* multf             = (float*)(ws + alloc(BB * 4));                    // 16 KB
    int* Ucnt                = (int*)(ws + alloc(4));
    unsigned short* pos2slot = (unsigned short*)(ws + alloc(BB * 2));           // 8 KB
    float* partial           = (float*)(ws + alloc(128 * IN_DIM * 4));          // 128 KB
    float* m1                = (float*)(ws + alloc(IN_DIM * 4));
    float* rs1               = (float*)(ws + alloc(IN_DIM * 4));
    float* m2                = (float*)(ws + alloc(RR * OUT * 4));
    float* rs2               = (float*)(ws + alloc(RR * OUT * 4));
    float* xn_c              = (float*)(ws + alloc((size_t)BB * IN_DIM * 4));   // 4 MB
    unsigned short* cols     = (unsigned short*)(ws + alloc((size_t)RR * BB * CAPD * 2)); // 3.1 MB
    int* cnt                 = (int*)(ws + alloc((size_t)RR * BB * 4));         // 48 KB
    float* dinv              = (float*)(ws + alloc((size_t)RR * BB * 4));       // 48 KB
    float* h1                = (float*)(ws + alloc((size_t)RR * BB * HID * 4)); // 6.3 MB
    float* h2                = (float*)(ws + alloc((size_t)RR * BB * OUT * 4)); // 3.1 MB

    prep_k<<<1, 1024, 0, stream>>>(bn, memb, rankg, nodeof, multf, Ucnt, pos2slot);
    bn1_partial_k<<<64, 256, 0, stream>>>(feat, nodeof, multf, Ucnt, partial);
    bn1_final_k<<<1, 256, 0, stream>>>(partial, m1, rs1);
    xn_c_k<<<BB, 256, 0, stream>>>(feat, nodeof, Ucnt, m1, rs1, g1, b1, xn_c);
    build_k<<<RR * BB, 256, 0, stream>>>(adj, nodeof, Ucnt, memb, rankg, multf, cols, cnt, dinv);
    layer1_k<<<RR * (BB / 4), 256, 0, stream>>>(xn_c, cols, cnt, dinv, multf, Ucnt, w1, h1);
    layer2_k<<<RR * (BB / 4), 256, 0, stream>>>(h1, cols, cnt, dinv, multf, Ucnt, w2, h2);
    bn2_stats_k<<<RR * OUT, 256, 0, stream>>>(h2, multf, Ucnt, m2, rs2);
    finalize_k<<<(BB * OUT + 255) / 256, 256, 0, stream>>>(h2, pos2slot, m2, rs2, g2, b2, out);
}

// Round 5
// 172.059 us; speedup vs baseline: 1.1534x; 1.1534x over previous
//
#include <hip/hip_runtime.h>
#include <hip/hip_bf16.h>

// Problem constants (match reference)
#define RR 3
#define NN 8192
#define BB 4096
#define IN_DIM 256
#define HID 128
#define OUT 64
#define CAPD 128     // padded list capacity (unique nbr nodes ~ Binom(3224,0.01) ~ 32±5.7)
#define EPS 1e-5f
#define MWN (NN / 64)   // 128 mask words over node space
#define MLPB 16         // slots per MLP block

// ---- prep: multiplicity, membership bitmap, rank compaction, pos->slot ----
__global__ __launch_bounds__(1024) void prep_k(const int* __restrict__ bn,
                                               unsigned long long* __restrict__ memb,
                                               unsigned short* __restrict__ rankg,
                                               unsigned short* __restrict__ nodeof,
                                               float* __restrict__ multf,
                                               int* __restrict__ Ucnt,
                                               unsigned short* __restrict__ pos2slot) {
    __shared__ int smult[NN];                 // 32 KB
    __shared__ unsigned short srank[NN];      // 16 KB
    __shared__ unsigned long long smemb[MWN]; // 1 KB
    __shared__ int sbase[MWN + 1];
    int t = threadIdx.x;
    for (int u = t; u < NN; u += 1024) smult[u] = 0;
    __syncthreads();
    for (int i = t; i < BB; i += 1024) atomicAdd(&smult[bn[i]], 1);
    __syncthreads();
    if (t < MWN) {
        unsigned long long w = 0;
        for (int b = 0; b < 64; ++b) if (smult[t * 64 + b]) w |= (1ull << b);
        smemb[t] = w;
        memb[t] = w;
    }
    __syncthreads();
    if (t == 0) {
        int acc = 0;
        for (int m = 0; m < MWN; ++m) { sbase[m] = acc; acc += (int)__popcll(smemb[m]); }
        sbase[MWN] = acc;
        *Ucnt = acc;
    }
    __syncthreads();
    if (t < MWN) {
        unsigned long long w = smemb[t];
        int p = sbase[t];
        while (w) {
            int b = __builtin_ctzll(w); w &= w - 1;
            int u = t * 64 + b;
            srank[u] = (unsigned short)p;
            rankg[u] = (unsigned short)p;
            nodeof[p] = (unsigned short)u;
            multf[p]  = (float)smult[u];
            ++p;
        }
    }
    __syncthreads();
    for (int i = t; i < BB; i += 1024) pos2slot[i] = srank[bn[i]];
}

// ---- BN1 stats: per-column mean/rstd over gathered x (positions) ----
__global__ __launch_bounds__(256) void bn1_stats_k(const float* __restrict__ feat,
                                                   const int* __restrict__ bn,
                                                   float* __restrict__ m1,
                                                   float* __restrict__ rs1) {
    int c = blockIdx.x;  // 0..IN_DIM-1
    float s = 0.f, q = 0.f;
    for (int i = threadIdx.x; i < BB; i += 256) {
        float v = feat[(size_t)bn[i] * IN_DIM + c];
        s += v; q += v * v;
    }
    int lane = threadIdx.x & 63, wv = threadIdx.x >> 6;
    for (int o = 32; o; o >>= 1) { s += __shfl_down(s, o); q += __shfl_down(q, o); }
    __shared__ float ps[4], pq[4];
    if (lane == 0) { ps[wv] = s; pq[wv] = q; }
    __syncthreads();
    if (threadIdx.x == 0) {
        float S = ps[0] + ps[1] + ps[2] + ps[3];
        float Q = pq[0] + pq[1] + pq[2] + pq[3];
        float m = S / BB;
        float v = Q / BB - m * m;   // biased variance
        m1[c] = m;
        rs1[c] = rsqrtf(v + EPS);
    }
}

// ---- xn per unique node slot: xn_c[s] = BN1(feat[nodeof[s]]) ----
__global__ __launch_bounds__(256) void xn_c_k(const float* __restrict__ feat,
                                              const unsigned short* __restrict__ nodeof,
                                              const int* __restrict__ Ucnt,
                                              const float* __restrict__ m1,
                                              const float* __restrict__ rs1,
                                              const float* __restrict__ g1,
                                              const float* __restrict__ b1,
                                              float* __restrict__ xn_c) {
    int s = blockIdx.x;
    if (s >= *Ucnt) return;
    int u = nodeof[s];
    int c = threadIdx.x;
    float v = feat[(size_t)u * IN_DIM + c];
    xn_c[(size_t)s * IN_DIM + c] = (v - m1[c]) * rs1[c] * g1[c] + b1[c];
}

// ---- build per (r, slot): coalesced row read -> bits -> AND membership -> list ----
__global__ __launch_bounds__(256) void build_k(const float* __restrict__ adj,
                                               const unsigned short* __restrict__ nodeof,
                                               const int* __restrict__ Ucnt,
                                               const unsigned long long* __restrict__ memb,
                                               const unsigned short* __restrict__ rankg,
                                               const float* __restrict__ multf,
                                               unsigned short* __restrict__ cols,
                                               int* __restrict__ cnt,
                                               float* __restrict__ dinv) {
    int blk = blockIdx.x;                   // r*4096 + s
    int r = blk >> 12, s = blk & (BB - 1);
    if (s >= *Ucnt) return;
    int u = nodeof[s];
    __shared__ unsigned char nib[2048];
    __shared__ unsigned int rawb[256];
    __shared__ unsigned long long sel[MWN];
    __shared__ int sbase[MWN + 1];
    __shared__ float pdeg[4];
    int t = threadIdx.x;
    // phase A: coalesced read of the 8192-float adjacency row; compress to bits
    const float4* ar4 = (const float4*)(adj + ((size_t)r * NN + u) * NN);
    #pragma unroll
    for (int ch = 0; ch < 8; ++ch) {
        float4 v = ar4[ch * 256 + t];
        nib[ch * 256 + t] = (unsigned char)((v.x != 0.f) | ((v.y != 0.f) << 1) |
                                            ((v.z != 0.f) << 2) | ((v.w != 0.f) << 3));
    }
    __syncthreads();
    {   // assemble u32 word t: cols [32t, 32t+32)
        unsigned long long x = *(const unsigned long long*)&nib[t * 8];
        x = (x | (x >> 4))  & 0x00FF00FF00FF00FFull;
        x = (x | (x >> 8))  & 0x0000FFFF0000FFFFull;
        x = (x | (x >> 16));
        rawb[t] = (unsigned int)x;
    }
    __syncthreads();
    // phase B: select member columns = raw & memb
    if (t < MWN) {
        unsigned long long w = ((unsigned long long)rawb[2 * t + 1] << 32) | rawb[2 * t];
        sel[t] = w & memb[t];
    }
    __syncthreads();
    // phase C: exclusive scan of word popcounts (wave 0, 2 words/lane)
    if (t < 64) {
        int p0 = (int)__popcll(sel[2 * t]);
        int p1 = (int)__popcll(sel[2 * t + 1]);
        int x = p0 + p1, xs = x;
        for (int o = 1; o < 64; o <<= 1) { int y = __shfl_up(xs, o); if (t >= o) xs += y; }
        sbase[2 * t]     = xs - x;
        sbase[2 * t + 1] = xs - p1;
        if (t == 63) sbase[MWN] = xs;
    }
    __syncthreads();
    // phase D: emit slot list + multiplicity-weighted degree
    float wdeg = 0.f;
    if (t < MWN) {
        unsigned long long w = sel[t];
        int p = sbase[t];
        unsigned short* cb = cols + (size_t)blk * CAPD;
        while (w) {
            int b = __builtin_ctzll(w); w &= w - 1;
            int v = t * 64 + b;
            int rv = rankg[v];
            if (p < CAPD) cb[p] = (unsigned short)rv;
            wdeg += multf[rv];
            ++p;
        }
    }
    int lane = t & 63, wv = t >> 6;
    for (int o = 32; o; o >>= 1) wdeg += __shfl_down(wdeg, o);
    if (lane == 0) pdeg[wv] = wdeg;
    __syncthreads();
    if (t == 0) {
        int tot = sbase[MWN];
        cnt[blk] = tot < CAPD ? tot : CAPD;
        dinv[blk] = rsqrtf(pdeg[0] + pdeg[1] + pdeg[2] + pdeg[3] + 1.0f);  // +1 from eye
    }
}

// ---- layer1 aggregation: y1[blk] = A_hat row applied to xn_c (256 cols) ----
__global__ __launch_bounds__(256) void layer1_agg_k(const float* __restrict__ xn_c,
                                                    const unsigned short* __restrict__ cols,
                                                    const int* __restrict__ cnt,
                                                    const float* __restrict__ dinv,
                                                    const float* __restrict__ multf,
                                                    const int* __restrict__ Ucnt,
                                                    float* __restrict__ y1) {
    int blk = blockIdx.x;                // r*4096 + s
    int r = blk >> 12, s = blk & (BB - 1);
    if (s >= *Ucnt) return;
    int c = threadIdx.x;
    __shared__ unsigned short scl[CAPD];
    __shared__ float swl[CAPD];
    int n = cnt[blk];
    if (c < n) {
        int sl = cols[(size_t)blk * CAPD + c];
        scl[c] = (unsigned short)sl;
        swl[c] = multf[sl] * dinv[(r << 12) + sl];
    }
    __syncthreads();
    float di = dinv[blk];
    float acc = di * xn_c[(size_t)s * IN_DIM + c];      // eye diagonal term
    #pragma unroll 4
    for (int k = 0; k < n; ++k) {
        acc += swl[k] * xn_c[(size_t)scl[k] * IN_DIM + c];
    }
    y1[(size_t)blk * IN_DIM + c] = acc * di;
}

// ---- MLP1: h1 = sigmoid(elu(y1 @ w1)); 16 slots/block, w1 amortized ----
__global__ __launch_bounds__(256) void mlp1_k(const float* __restrict__ y1,
                                              const int* __restrict__ Ucnt,
                                              const float* __restrict__ w1,
                                              float* __restrict__ h1) {
    int blk = blockIdx.x;                // r*(BB/MLPB) + chunk
    int r = blk / (BB / MLPB), base = (blk % (BB / MLPB)) * MLPB;
    int U = *Ucnt;
    if (base >= U) return;
    int t = threadIdx.x;
    __shared__ float ys[MLPB][IN_DIM];   // 16 KB
    #pragma unroll
    for (int s = 0; s < MLPB; ++s) {
        int slot = base + s;
        ys[s][t] = (slot < U) ? y1[((size_t)(r << 12) + slot) * IN_DIM + t] : 0.f;
    }
    __syncthreads();
    int c = t & 127, g = t >> 7;         // g in {0,1}: slots g*8 .. g*8+7
    float acc[8] = {0.f};
    for (int k = 0; k < IN_DIM; ++k) {
        float wv = w1[k * HID + c];
        #pragma unroll
        for (int j = 0; j < 8; ++j) acc[j] += ys[g * 8 + j][k] * wv;
    }
    #pragma unroll
    for (int j = 0; j < 8; ++j) {
        int slot = base + g * 8 + j;
        if (slot < U) {
            float z = acc[j];
            float e = z > 0.f ? z : expm1f(z);            // elu
            h1[((size_t)(r << 12) + slot) * HID + c] = 1.f / (1.f + expf(-e));  // sigmoid
        }
    }
}

// ---- layer2 aggregation: y2[blk] = A_hat row applied to h1 (128 cols) ----
__global__ __launch_bounds__(128) void layer2_agg_k(const float* __restrict__ h1,
                                                    const unsigned short* __restrict__ cols,
                                                    const int* __restrict__ cnt,
                                                    const float* __restrict__ dinv,
                                                    const float* __restrict__ multf,
                                                    const int* __restrict__ Ucnt,
                                                    float* __restrict__ y2) {
    int blk = blockIdx.x;
    int r = blk >> 12, s = blk & (BB - 1);
    if (s >= *Ucnt) return;
    int c = threadIdx.x;                 // 0..127
    __shared__ unsigned short scl[CAPD];
    __shared__ float swl[CAPD];
    int n = cnt[blk];
    if (c < n) {
        int sl = cols[(size_t)blk * CAPD + c];
        scl[c] = (unsigned short)sl;
        swl[c] = multf[sl] * dinv[(r << 12) + sl];
    }
    __syncthreads();
    const float* h1r = h1 + ((size_t)(r << 12)) * HID;
    float di = dinv[blk];
    float acc = di * h1r[(size_t)s * HID + c];
    #pragma unroll 4
    for (int k = 0; k < n; ++k) {
        acc += swl[k] * h1r[(size_t)scl[k] * HID + c];
    }
    y2[(size_t)blk * HID + c] = acc * di;
}

// ---- MLP2: h2 = elu(y2 @ w2); 16 slots/block, w2 amortized ----
__global__ __launch_bounds__(256) void mlp2_k(const float* __restrict__ y2,
                                              const int* __restrict__ Ucnt,
                                              const float* __restrict__ w2,
                                              float* __restrict__ h2) {
    int blk = blockIdx.x;
    int r = blk / (BB / MLPB), base = (blk % (BB / MLPB)) * MLPB;
    int U = *Ucnt;
    if (base >= U) return;
    int t = threadIdx.x;
    __shared__ float ys[MLPB][HID];      // 8 KB
    #pragma unroll
    for (int s = t >> 7; s < MLPB; s += 2) {
        int slot = base + s;
        ys[s][t & 127] = (slot < U) ? y2[((size_t)(r << 12) + slot) * HID + (t & 127)] : 0.f;
    }
    __syncthreads();
    int c = t & 63, g = t >> 6;          // g in 0..3: slots g*4 .. g*4+3
    float acc[4] = {0.f};
    for (int k = 0; k < HID; ++k) {
        float wv = w2[k * OUT + c];
        #pragma unroll
        for (int j = 0; j < 4; ++j) acc[j] += ys[g * 4 + j][k] * wv;
    }
    #pragma unroll
    for (int j = 0; j < 4; ++j) {
        int slot = base + g * 4 + j;
        if (slot < U) {
            float z = acc[j];
            h2[((size_t)(r << 12) + slot) * OUT + c] = z > 0.f ? z : expm1f(z);  // elu
        }
    }
}

// ---- BN2 stats per (relation, column): multiplicity-weighted over slots ----
__global__ __launch_bounds__(256) void bn2_stats_k(const float* __restrict__ h2,
                                                   const float* __restrict__ multf,
                                                   const int* __restrict__ Ucnt,
                                                   float* __restrict__ m2,
                                                   float* __restrict__ rs2) {
    int ro = blockIdx.x;             // r*OUT + o
    int r = ro >> 6, o = ro & (OUT - 1);
    int U = *Ucnt;
    float s = 0.f, q = 0.f;
    for (int sl = threadIdx.x; sl < U; sl += 256) {
        float m = multf[sl];
        float v = h2[(size_t)((r << 12) + sl) * OUT + o];
        s += m * v; q += m * v * v;
    }
    int lane = threadIdx.x & 63, wv = threadIdx.x >> 6;
    for (int off = 32; off; off >>= 1) { s += __shfl_down(s, off); q += __shfl_down(q, off); }
    __shared__ float ps[4], pq[4];
    if (lane == 0) { ps[wv] = s; pq[wv] = q; }
    __syncthreads();
    if (threadIdx.x == 0) {
        float S = ps[0] + ps[1] + ps[2] + ps[3];
        float Q = pq[0] + pq[1] + pq[2] + pq[3];
        float m = S / BB;                 // sum of mult == BB positions
        float v = Q / BB - m * m;
        m2[ro] = m;
        rs2[ro] = rsqrtf(v + EPS);
    }
}

// ---- finalize: out[i] = relu(mean_r BN2(h2[r, slot(i)])) ----
__global__ __launch_bounds__(256) void finalize_k(const float* __restrict__ h2,
                                                  const unsigned short* __restrict__ pos2slot,
                                                  const float* __restrict__ m2,
                                                  const float* __restrict__ rs2,
                                                  const float* __restrict__ g2,
                                                  const float* __restrict__ b2,
                                                  float* __restrict__ out) {
    int idx = blockIdx.x * 256 + threadIdx.x;  // i*OUT + o
    if (idx >= BB * OUT) return;
    int i = idx >> 6, o = idx & (OUT - 1);
    int sl = pos2slot[i];
    float s = 0.f;
    for (int r = 0; r < RR; ++r) {
        float v = h2[(size_t)((r << 12) + sl) * OUT + o];
        s += (v - m2[r * OUT + o]) * rs2[r * OUT + o] * g2[o] + b2[o];
    }
    s *= (1.0f / RR);
    out[idx] = s > 0.f ? s : 0.f;
}

extern "C" void kernel_launch(void* const* d_in, const int* in_sizes, int n_in,
                              void* d_out, int out_size, void* d_ws, size_t ws_size,
                              hipStream_t stream) {
    const float* feat = (const float*)d_in[0];
    const float* adj  = (const float*)d_in[1];
    const int*   bn   = (const int*)d_in[2];
    const float* w1   = (const float*)d_in[3];
    const float* w2   = (const float*)d_in[4];
    const float* g1   = (const float*)d_in[5];
    const float* b1   = (const float*)d_in[6];
    const float* g2   = (const float*)d_in[7];
    const float* b2   = (const float*)d_in[8];
    float* out = (float*)d_out;

    // workspace layout (256-aligned offsets)
    char* ws = (char*)d_ws;
    size_t off = 0;
    auto alloc = [&](size_t bytes) { size_t o = off; off += (bytes + 255) & ~(size_t)255; return o; };
    unsigned long long* memb = (unsigned long long*)(ws + alloc(MWN * 8));      // 1 KB
    unsigned short* rankg    = (unsigned short*)(ws + alloc(NN * 2));           // 16 KB
    unsigned short* nodeof   = (unsigned short*)(ws + alloc(BB * 2));           // 8 KB
    float* multf             = (float*)(ws + alloc(BB * 4));                    // 16 KB
    int* Ucnt                = (int*)(ws + alloc(4));
    unsigned short* pos2slot = (unsigned short*)(ws + alloc(BB * 2));           // 8 KB
    float* m1                = (float*)(ws + alloc(IN_DIM * 4));
    float* rs1               = (float*)(ws + alloc(IN_DIM * 4));
    float* m2                = (float*)(ws + alloc(RR * OUT * 4));
    float* rs2               = (float*)(ws + alloc(RR * OUT * 4));
    float* xn_c              = (float*)(ws + alloc((size_t)BB * IN_DIM * 4));   // 4 MB
    unsigned short* cols     = (unsigned short*)(ws + alloc((size_t)RR * BB * CAPD * 2)); // 3.1 MB
    int* cnt                 = (int*)(ws + alloc((size_t)RR * BB * 4));         // 48 KB
    float* dinv              = (float*)(ws + alloc((size_t)RR * BB * 4));       // 48 KB
    float* y1                = (float*)(ws + alloc((size_t)RR * BB * IN_DIM * 4)); // 12.6 MB
    float* h1                = (float*)(ws + alloc((size_t)RR * BB * HID * 4)); // 6.3 MB
    float* y2                = (float*)(ws + alloc((size_t)RR * BB * HID * 4)); // 6.3 MB
    float* h2                = (float*)(ws + alloc((size_t)RR * BB * OUT * 4)); // 3.1 MB

    prep_k<<<1, 1024, 0, stream>>>(bn, memb, rankg, nodeof, multf, Ucnt, pos2slot);
    bn1_stats_k<<<IN_DIM, 256, 0, stream>>>(feat, bn, m1, rs1);
    xn_c_k<<<BB, 256, 0, stream>>>(feat, nodeof, Ucnt, m1, rs1, g1, b1, xn_c);
    build_k<<<RR * BB, 256, 0, stream>>>(adj, nodeof, Ucnt, memb, rankg, multf, cols, cnt, dinv);
    layer1_agg_k<<<RR * BB, 256, 0, stream>>>(xn_c, cols, cnt, dinv, multf, Ucnt, y1);
    mlp1_k<<<RR * (BB / MLPB), 256, 0, stream>>>(y1, Ucnt, w1, h1);
    layer2_agg_k<<<RR * BB, 128, 0, stream>>>(h1, cols, cnt, dinv, multf, Ucnt, y2);
    mlp2_k<<<RR * (BB / MLPB), 256, 0, stream>>>(y2, Ucnt, w2, h2);
    bn2_stats_k<<<RR * OUT, 256, 0, stream>>>(h2, multf, Ucnt, m2, rs2);
    finalize_k<<<(BB * OUT + 255) / 256, 256, 0, stream>>>(h2, pos2slot, m2, rs2, g2, b2, out);
}